// Round 1
// baseline (860.084 us; speedup 1.0000x reference)
//
#include <hip/hip_runtime.h>

#define NN 100000
#define EE 1600000
#define HH 64
#define GG 64

// ---------------- workspace layout (bytes) ----------------
// cnt      : int[NN]        @ 0
// cur      : int[NN]        @ 400000
// rowStart : int[NN+1]      @ 800000
// dinv     : float[NN]      @ 1200016
// srcs     : int[EE]        @ 1600016
// u        : float[NN*64]   @ 8000016   (16B aligned)
// hb       : float[NN*64]   @ 33600016  (16B aligned)
// gsum     : float[GG*64]   @ 59200016
// gcnt     : float[GG]      @ 59216400
// total ~56.5 MB

static inline int cdiv_h(int a, int b) { return (a + b - 1) / b; }

__global__ __launch_bounds__(256) void count_kernel(const int* __restrict__ ei,
                                                    int* __restrict__ cnt) {
    int e = blockIdx.x * 256 + threadIdx.x;
    if (e < EE) atomicAdd(&cnt[ei[EE + e]], 1);
}

__global__ __launch_bounds__(1024) void scan_kernel(const int* __restrict__ cnt,
                                                    int* __restrict__ rowStart) {
    const int T = 1024;
    const int CH = (NN + T - 1) / T;  // 98
    int t = threadIdx.x;
    int base = t * CH;
    int s = 0;
    for (int i = 0; i < CH; i++) {
        int idx = base + i;
        if (idx < NN) s += cnt[idx];
    }
    __shared__ int sums[T];
    sums[t] = s;
    __syncthreads();
    for (int off = 1; off < T; off <<= 1) {
        int v = (t >= off) ? sums[t - off] : 0;
        __syncthreads();
        sums[t] += v;
        __syncthreads();
    }
    int run = (t == 0) ? 0 : sums[t - 1];
    for (int i = 0; i < CH; i++) {
        int idx = base + i;
        if (idx < NN) {
            rowStart[idx] = run;
            run += cnt[idx];
        }
    }
    if (t == T - 1) rowStart[NN] = run;  // == EE
}

__global__ __launch_bounds__(256) void dinv_kernel(const int* __restrict__ cnt,
                                                   float* __restrict__ dinv) {
    int n = blockIdx.x * 256 + threadIdx.x;
    if (n < NN) dinv[n] = rsqrtf((float)cnt[n] + 1.0f);
}

__global__ __launch_bounds__(256) void place_kernel(const int* __restrict__ ei,
                                                    const int* __restrict__ rowStart,
                                                    int* __restrict__ cur,
                                                    int* __restrict__ srcs) {
    int e = blockIdx.x * 256 + threadIdx.x;
    if (e >= EE) return;
    int d = ei[EE + e];
    int p = rowStart[d] + atomicAdd(&cur[d], 1);
    srcs[p] = ei[e];
}

// u[n][:] = dinv[n] * (hin[n][:] @ W)   -- one thread per row
__global__ __launch_bounds__(256) void gemm_kernel(const float* __restrict__ hin,
                                                   const float* __restrict__ Wg,
                                                   const float* __restrict__ dinv,
                                                   float* __restrict__ u) {
    int n = blockIdx.x * 256 + threadIdx.x;
    if (n >= NN) return;
    const float* hr = hin + (size_t)n * 64;
    float acc[64];
#pragma unroll
    for (int j = 0; j < 64; j++) acc[j] = 0.0f;
#pragma unroll 2
    for (int k = 0; k < 64; k++) {
        float hk = hr[k];
        const float4* Wr = (const float4*)(Wg + (k << 6));
#pragma unroll
        for (int j = 0; j < 16; j++) {
            float4 w = Wr[j];
            acc[j * 4 + 0] = fmaf(hk, w.x, acc[j * 4 + 0]);
            acc[j * 4 + 1] = fmaf(hk, w.y, acc[j * 4 + 1]);
            acc[j * 4 + 2] = fmaf(hk, w.z, acc[j * 4 + 2]);
            acc[j * 4 + 3] = fmaf(hk, w.w, acc[j * 4 + 3]);
        }
    }
    float dv = dinv[n];
    float4* uo = (float4*)(u + (size_t)n * 64);
#pragma unroll
    for (int j = 0; j < 16; j++) {
        float4 o;
        o.x = acc[j * 4 + 0] * dv;
        o.y = acc[j * 4 + 1] * dv;
        o.z = acc[j * 4 + 2] * dv;
        o.w = acc[j * 4 + 3] * dv;
        uo[j] = o;
    }
}

// h_out[n] = relu(dinv[n]*(u[n] + sum_{src in CSR[n]} u[src]) + b)
// one wave per node, lane = feature
__global__ __launch_bounds__(256) void agg_kernel(const float* __restrict__ u,
                                                  const int* __restrict__ srcs,
                                                  const int* __restrict__ rowStart,
                                                  const float* __restrict__ dinv,
                                                  const float* __restrict__ b,
                                                  float* __restrict__ hout) {
    int wid = (blockIdx.x * 256 + threadIdx.x) >> 6;
    int lane = threadIdx.x & 63;
    if (wid >= NN) return;
    int n = wid;
    float acc = u[((size_t)n << 6) + lane];
    int e = rowStart[n];
    int e1 = rowStart[n + 1];
    for (; e + 3 < e1; e += 4) {
        int s0 = srcs[e + 0];
        int s1 = srcs[e + 1];
        int s2 = srcs[e + 2];
        int s3 = srcs[e + 3];
        float v0 = u[((size_t)s0 << 6) + lane];
        float v1 = u[((size_t)s1 << 6) + lane];
        float v2 = u[((size_t)s2 << 6) + lane];
        float v3 = u[((size_t)s3 << 6) + lane];
        acc += v0;
        acc += v1;
        acc += v2;
        acc += v3;
    }
    for (; e < e1; e++) {
        int s0 = srcs[e];
        acc += u[((size_t)s0 << 6) + lane];
    }
    float v = fmaf(dinv[n], acc, b[lane]);
    hout[((size_t)n << 6) + lane] = fmaxf(v, 0.0f);
}

// mean-pool partials: one wave per 256 contiguous nodes (batch is sorted)
__global__ __launch_bounds__(256) void pool_kernel(const float* __restrict__ hbuf,
                                                   const int* __restrict__ batch,
                                                   float* __restrict__ gsum,
                                                   float* __restrict__ gcnt) {
    int wave = (blockIdx.x * 256 + threadIdx.x) >> 6;
    int lane = threadIdx.x & 63;
    int n0 = wave * 256;
    if (n0 >= NN) return;
    int n1 = n0 + 256;
    if (n1 > NN) n1 = NN;
    int curg = batch[n0];
    float racc = 0.0f;
    float rcnt = 0.0f;
    for (int n = n0; n < n1; n++) {
        int g = batch[n];
        if (g != curg) {
            atomicAdd(&gsum[curg * 64 + lane], racc);
            if (lane == 0) atomicAdd(&gcnt[curg], rcnt);
            racc = 0.0f;
            rcnt = 0.0f;
            curg = g;
        }
        racc += hbuf[((size_t)n << 6) + lane];
        rcnt += 1.0f;
    }
    atomicAdd(&gsum[curg * 64 + lane], racc);
    if (lane == 0) atomicAdd(&gcnt[curg], rcnt);
}

__global__ __launch_bounds__(128) void final_kernel(const float* __restrict__ gsum,
                                                    const float* __restrict__ gcnt,
                                                    const float* __restrict__ Wlin,
                                                    const float* __restrict__ blin,
                                                    float* __restrict__ out) {
    int t = threadIdx.x;  // 128 = G*C
    int g = t >> 1;
    int c = t & 1;
    float cnt = fmaxf(gcnt[g], 1.0f);
    float s = 0.0f;
#pragma unroll
    for (int k = 0; k < 64; k++) s = fmaf(gsum[g * 64 + k], Wlin[k * 2 + c], s);
    out[t] = s / cnt + blin[c];
}

extern "C" void kernel_launch(void* const* d_in, const int* in_sizes, int n_in,
                              void* d_out, int out_size, void* d_ws, size_t ws_size,
                              hipStream_t stream) {
    const float* x    = (const float*)d_in[0];
    const int*   ei   = (const int*)d_in[1];
    const int*   batch = (const int*)d_in[2];
    const float* W0   = (const float*)d_in[3];
    const float* b0   = (const float*)d_in[4];
    const float* W1   = (const float*)d_in[5];
    const float* b1   = (const float*)d_in[6];
    const float* W2   = (const float*)d_in[7];
    const float* b2   = (const float*)d_in[8];
    const float* Wlin = (const float*)d_in[9];
    const float* blin = (const float*)d_in[10];
    float* out = (float*)d_out;

    char* ws = (char*)d_ws;
    int*   cnt      = (int*)(ws + 0);
    int*   cur      = (int*)(ws + 400000);
    int*   rowStart = (int*)(ws + 800000);
    float* dinv     = (float*)(ws + 1200016);
    int*   srcs     = (int*)(ws + 1600016);
    float* u        = (float*)(ws + 8000016);
    float* hb       = (float*)(ws + 33600016);
    float* gsum     = (float*)(ws + 59200016);
    float* gcnt     = (float*)(ws + 59216400);

    // zero: cnt+cur (adjacent), gsum+gcnt (adjacent)
    hipMemsetAsync(ws, 0, 800000, stream);
    hipMemsetAsync(ws + 59200016, 0, 16640, stream);

    // CSR build + normalization
    count_kernel<<<EE / 256, 256, 0, stream>>>(ei, cnt);
    scan_kernel<<<1, 1024, 0, stream>>>(cnt, rowStart);
    dinv_kernel<<<cdiv_h(NN, 256), 256, 0, stream>>>(cnt, dinv);
    place_kernel<<<EE / 256, 256, 0, stream>>>(ei, rowStart, cur, srcs);

    int gemm_blocks = cdiv_h(NN, 256);
    int agg_blocks = cdiv_h(NN, 4);  // 4 waves (nodes) per block

    // layer 0
    gemm_kernel<<<gemm_blocks, 256, 0, stream>>>(x, W0, dinv, u);
    agg_kernel<<<agg_blocks, 256, 0, stream>>>(u, srcs, rowStart, dinv, b0, hb);
    // layer 1
    gemm_kernel<<<gemm_blocks, 256, 0, stream>>>(hb, W1, dinv, u);
    agg_kernel<<<agg_blocks, 256, 0, stream>>>(u, srcs, rowStart, dinv, b1, hb);
    // layer 2
    gemm_kernel<<<gemm_blocks, 256, 0, stream>>>(hb, W2, dinv, u);
    agg_kernel<<<agg_blocks, 256, 0, stream>>>(u, srcs, rowStart, dinv, b2, hb);

    // pooling + classifier
    int pool_waves = cdiv_h(NN, 256);                // 391
    int pool_blocks = cdiv_h(pool_waves, 4);         // 98
    pool_kernel<<<pool_blocks, 256, 0, stream>>>(hb, batch, gsum, gcnt);
    final_kernel<<<1, 128, 0, stream>>>(gsum, gcnt, Wlin, blin, out);
}

// Round 2
// 698.491 us; speedup vs baseline: 1.2313x; 1.2313x over previous
//
#include <hip/hip_runtime.h>

#define NN 100000
#define EE 1600000
#define HH 64
#define GG 64
#define NB 391  // cdiv(NN,256)

// ---------------- workspace layout (bytes) ----------------
// cnt      : int[NN]        @ 0
// cur      : int[NN]        @ 400000
// rowStart : int[NN+1]      @ 800000
// dinv     : float[NN]      @ 1200016
// srcs     : int[EE]        @ 1600016
// u        : float[NN*64]   @ 8000016   (16B aligned)
// hb       : float[NN*64]   @ 33600016  (16B aligned)
// gsum     : float[GG*64]   @ 59200016
// gcnt     : float[GG]      @ 59216400
// bsums    : int[NB]        @ 59220496
// boffs    : int[NB]        @ 59222096

static inline int cdiv_h(int a, int b) { return (a + b - 1) / b; }

__global__ __launch_bounds__(256) void count_kernel(const int* __restrict__ ei,
                                                    int* __restrict__ cnt) {
    int e = blockIdx.x * 256 + threadIdx.x;
    if (e < EE) atomicAdd(&cnt[ei[EE + e]], 1);
}

// ---- hierarchical scan: phase 1 (per-block sums) ----
__global__ __launch_bounds__(256) void scan1_kernel(const int* __restrict__ cnt,
                                                    int* __restrict__ bsums) {
    int i = blockIdx.x * 256 + threadIdx.x;
    int v = (i < NN) ? cnt[i] : 0;
#pragma unroll
    for (int o = 32; o > 0; o >>= 1) v += __shfl_down(v, o, 64);
    __shared__ int ws[4];
    if ((threadIdx.x & 63) == 0) ws[threadIdx.x >> 6] = v;
    __syncthreads();
    if (threadIdx.x == 0) bsums[blockIdx.x] = ws[0] + ws[1] + ws[2] + ws[3];
}

// ---- phase 2: scan 391 block sums in one block ----
__global__ __launch_bounds__(512) void scan2_kernel(const int* __restrict__ bsums,
                                                    int* __restrict__ boffs) {
    __shared__ int s[512];
    int t = threadIdx.x;
    int v = (t < NB) ? bsums[t] : 0;
    s[t] = v;
    __syncthreads();
    for (int off = 1; off < 512; off <<= 1) {
        int u = (t >= off) ? s[t - off] : 0;
        __syncthreads();
        s[t] += u;
        __syncthreads();
    }
    if (t < NB) boffs[t] = s[t] - v;  // exclusive
}

// ---- phase 3: in-block exclusive scan + block offset; also dinv ----
__global__ __launch_bounds__(256) void scan3_kernel(const int* __restrict__ cnt,
                                                    const int* __restrict__ boffs,
                                                    int* __restrict__ rowStart,
                                                    float* __restrict__ dinv) {
    int t = threadIdx.x;
    int i = blockIdx.x * 256 + t;
    int v = (i < NN) ? cnt[i] : 0;
    __shared__ int s[256];
    s[t] = v;
    __syncthreads();
    for (int off = 1; off < 256; off <<= 1) {
        int u = (t >= off) ? s[t - off] : 0;
        __syncthreads();
        s[t] += u;
        __syncthreads();
    }
    int incl = s[t];
    if (i < NN) {
        rowStart[i] = boffs[blockIdx.x] + incl - v;
        dinv[i] = rsqrtf((float)v + 1.0f);
    }
    if (i == NN - 1) rowStart[NN] = boffs[blockIdx.x] + incl;  // == EE
}

__global__ __launch_bounds__(256) void place_kernel(const int* __restrict__ ei,
                                                    const int* __restrict__ rowStart,
                                                    int* __restrict__ cur,
                                                    int* __restrict__ srcs) {
    int e = blockIdx.x * 256 + threadIdx.x;
    if (e >= EE) return;
    int d = ei[EE + e];
    int p = rowStart[d] + atomicAdd(&cur[d], 1);
    srcs[p] = ei[e];
}

// u[n][:] = dinv[n] * (hin[n][:] @ W)   -- one thread per row
__global__ __launch_bounds__(256) void gemm_kernel(const float* __restrict__ hin,
                                                   const float* __restrict__ Wg,
                                                   const float* __restrict__ dinv,
                                                   float* __restrict__ u) {
    int n = blockIdx.x * 256 + threadIdx.x;
    if (n >= NN) return;
    const float* hr = hin + (size_t)n * 64;
    float acc[64];
#pragma unroll
    for (int j = 0; j < 64; j++) acc[j] = 0.0f;
#pragma unroll 2
    for (int k = 0; k < 64; k++) {
        float hk = hr[k];
        const float4* Wr = (const float4*)(Wg + (k << 6));
#pragma unroll
        for (int j = 0; j < 16; j++) {
            float4 w = Wr[j];
            acc[j * 4 + 0] = fmaf(hk, w.x, acc[j * 4 + 0]);
            acc[j * 4 + 1] = fmaf(hk, w.y, acc[j * 4 + 1]);
            acc[j * 4 + 2] = fmaf(hk, w.z, acc[j * 4 + 2]);
            acc[j * 4 + 3] = fmaf(hk, w.w, acc[j * 4 + 3]);
        }
    }
    float dv = dinv[n];
    float4* uo = (float4*)(u + (size_t)n * 64);
#pragma unroll
    for (int j = 0; j < 16; j++) {
        float4 o;
        o.x = acc[j * 4 + 0] * dv;
        o.y = acc[j * 4 + 1] * dv;
        o.z = acc[j * 4 + 2] * dv;
        o.w = acc[j * 4 + 3] * dv;
        uo[j] = o;
    }
}

// h_out[n] = relu(dinv[n]*(u[n] + sum_{src in CSR[n]} u[src]) + b)
// one wave per node, lane = feature
__global__ __launch_bounds__(256) void agg_kernel(const float* __restrict__ u,
                                                  const int* __restrict__ srcs,
                                                  const int* __restrict__ rowStart,
                                                  const float* __restrict__ dinv,
                                                  const float* __restrict__ b,
                                                  float* __restrict__ hout) {
    int wid = (blockIdx.x * 256 + threadIdx.x) >> 6;
    int lane = threadIdx.x & 63;
    if (wid >= NN) return;
    int n = wid;
    float acc = u[((size_t)n << 6) + lane];
    int e = rowStart[n];
    int e1 = rowStart[n + 1];
    for (; e + 3 < e1; e += 4) {
        int s0 = srcs[e + 0];
        int s1 = srcs[e + 1];
        int s2 = srcs[e + 2];
        int s3 = srcs[e + 3];
        float v0 = u[((size_t)s0 << 6) + lane];
        float v1 = u[((size_t)s1 << 6) + lane];
        float v2 = u[((size_t)s2 << 6) + lane];
        float v3 = u[((size_t)s3 << 6) + lane];
        acc += v0;
        acc += v1;
        acc += v2;
        acc += v3;
    }
    for (; e < e1; e++) {
        int s0 = srcs[e];
        acc += u[((size_t)s0 << 6) + lane];
    }
    float v = fmaf(dinv[n], acc, b[lane]);
    hout[((size_t)n << 6) + lane] = fmaxf(v, 0.0f);
}

// mean-pool partials: one wave per 256 contiguous nodes (batch is sorted)
__global__ __launch_bounds__(256) void pool_kernel(const float* __restrict__ hbuf,
                                                   const int* __restrict__ batch,
                                                   float* __restrict__ gsum,
                                                   float* __restrict__ gcnt) {
    int wave = (blockIdx.x * 256 + threadIdx.x) >> 6;
    int lane = threadIdx.x & 63;
    int n0 = wave * 256;
    if (n0 >= NN) return;
    int n1 = n0 + 256;
    if (n1 > NN) n1 = NN;
    int curg = batch[n0];
    float racc = 0.0f;
    float rcnt = 0.0f;
    for (int n = n0; n < n1; n++) {
        int g = batch[n];
        if (g != curg) {
            atomicAdd(&gsum[curg * 64 + lane], racc);
            if (lane == 0) atomicAdd(&gcnt[curg], rcnt);
            racc = 0.0f;
            rcnt = 0.0f;
            curg = g;
        }
        racc += hbuf[((size_t)n << 6) + lane];
        rcnt += 1.0f;
    }
    atomicAdd(&gsum[curg * 64 + lane], racc);
    if (lane == 0) atomicAdd(&gcnt[curg], rcnt);
}

__global__ __launch_bounds__(128) void final_kernel(const float* __restrict__ gsum,
                                                    const float* __restrict__ gcnt,
                                                    const float* __restrict__ Wlin,
                                                    const float* __restrict__ blin,
                                                    float* __restrict__ out) {
    int t = threadIdx.x;  // 128 = G*C
    int g = t >> 1;
    int c = t & 1;
    float cnt = fmaxf(gcnt[g], 1.0f);
    float s = 0.0f;
#pragma unroll
    for (int k = 0; k < 64; k++) s = fmaf(gsum[g * 64 + k], Wlin[k * 2 + c], s);
    out[t] = s / cnt + blin[c];
}

extern "C" void kernel_launch(void* const* d_in, const int* in_sizes, int n_in,
                              void* d_out, int out_size, void* d_ws, size_t ws_size,
                              hipStream_t stream) {
    const float* x    = (const float*)d_in[0];
    const int*   ei   = (const int*)d_in[1];
    const int*   batch = (const int*)d_in[2];
    const float* W0   = (const float*)d_in[3];
    const float* b0   = (const float*)d_in[4];
    const float* W1   = (const float*)d_in[5];
    const float* b1   = (const float*)d_in[6];
    const float* W2   = (const float*)d_in[7];
    const float* b2   = (const float*)d_in[8];
    const float* Wlin = (const float*)d_in[9];
    const float* blin = (const float*)d_in[10];
    float* out = (float*)d_out;

    char* ws = (char*)d_ws;
    int*   cnt      = (int*)(ws + 0);
    int*   cur      = (int*)(ws + 400000);
    int*   rowStart = (int*)(ws + 800000);
    float* dinv     = (float*)(ws + 1200016);
    int*   srcs     = (int*)(ws + 1600016);
    float* u        = (float*)(ws + 8000016);
    float* hb       = (float*)(ws + 33600016);
    float* gsum     = (float*)(ws + 59200016);
    float* gcnt     = (float*)(ws + 59216400);
    int*   bsums    = (int*)(ws + 59220496);
    int*   boffs    = (int*)(ws + 59222096);

    // zero: cnt+cur (adjacent), gsum+gcnt (adjacent)
    hipMemsetAsync(ws, 0, 800000, stream);
    hipMemsetAsync(ws + 59200016, 0, 16640, stream);

    // CSR build + normalization (hierarchical scan)
    count_kernel<<<EE / 256, 256, 0, stream>>>(ei, cnt);
    scan1_kernel<<<NB, 256, 0, stream>>>(cnt, bsums);
    scan2_kernel<<<1, 512, 0, stream>>>(bsums, boffs);
    scan3_kernel<<<NB, 256, 0, stream>>>(cnt, boffs, rowStart, dinv);
    place_kernel<<<EE / 256, 256, 0, stream>>>(ei, rowStart, cur, srcs);

    int gemm_blocks = cdiv_h(NN, 256);
    int agg_blocks = cdiv_h(NN, 4);  // 4 waves (nodes) per block

    // layer 0
    gemm_kernel<<<gemm_blocks, 256, 0, stream>>>(x, W0, dinv, u);
    agg_kernel<<<agg_blocks, 256, 0, stream>>>(u, srcs, rowStart, dinv, b0, hb);
    // layer 1
    gemm_kernel<<<gemm_blocks, 256, 0, stream>>>(hb, W1, dinv, u);
    agg_kernel<<<agg_blocks, 256, 0, stream>>>(u, srcs, rowStart, dinv, b1, hb);
    // layer 2
    gemm_kernel<<<gemm_blocks, 256, 0, stream>>>(hb, W2, dinv, u);
    agg_kernel<<<agg_blocks, 256, 0, stream>>>(u, srcs, rowStart, dinv, b2, hb);

    // pooling + classifier
    int pool_waves = cdiv_h(NN, 256);                // 391
    int pool_blocks = cdiv_h(pool_waves, 4);         // 98
    pool_kernel<<<pool_blocks, 256, 0, stream>>>(hb, batch, gsum, gcnt);
    final_kernel<<<1, 128, 0, stream>>>(gsum, gcnt, Wlin, blin, out);
}

// Round 3
// 527.905 us; speedup vs baseline: 1.6292x; 1.3231x over previous
//
#include <hip/hip_runtime.h>
#include <hip/hip_fp16.h>

#define NN 100000
#define EE 1600000
#define HH 64
#define GG 64
#define NBK 391   // buckets of 256 nodes: dst>>8, ceil(100000/256)

// ---------------- workspace layout (bytes) ----------------
// rowStart : int[NN+1]    @ 0
// dinv     : float[NN]    @ 400128
// srcs     : int[EE]      @ 800128
// tmp      : int2[EE]     @ 7200128
// u (half) : half[NN*64]  @ 20000128
// hb       : float[NN*64] @ 32800128
// gsum     : float[4096]  @ 58400128
// gcnt     : float[64]    @ 58416512
// bcnt     : int[NBK]     @ 58416768
// bbase    : int[NBK+1]   @ 58418816
// bcur     : int[NBK]     @ 58420864

static inline int cdiv_h(int a, int b) { return (a + b - 1) / b; }

// ---- bucket histogram: 391 blocks x 4096 edges, LDS pre-aggregation ----
__global__ __launch_bounds__(256) void bcount_kernel(const int* __restrict__ ei,
                                                     int* __restrict__ bcnt) {
    __shared__ int h[NBK];
    for (int t = threadIdx.x; t < NBK; t += 256) h[t] = 0;
    __syncthreads();
    int base = blockIdx.x * 4096;
#pragma unroll
    for (int i = 0; i < 16; i++) {
        int e = base + i * 256 + threadIdx.x;
        if (e < EE) atomicAdd(&h[ei[EE + e] >> 8], 1);
    }
    __syncthreads();
    for (int t = threadIdx.x; t < NBK; t += 256)
        if (h[t]) atomicAdd(&bcnt[t], h[t]);
}

// ---- scan 391 bucket counts (1 block) ----
__global__ __launch_bounds__(512) void bscan_kernel(const int* __restrict__ bcnt,
                                                    int* __restrict__ bbase,
                                                    int* __restrict__ rowStart) {
    __shared__ int s[512];
    int t = threadIdx.x;
    int v = (t < NBK) ? bcnt[t] : 0;
    s[t] = v;
    __syncthreads();
    for (int off = 1; off < 512; off <<= 1) {
        int w = (t >= off) ? s[t - off] : 0;
        __syncthreads();
        s[t] += w;
        __syncthreads();
    }
    if (t < NBK) bbase[t] = s[t] - v;  // exclusive
    if (t == 0) { bbase[NBK] = EE; rowStart[NN] = EE; }
}

// ---- partition edges into buckets: 98 blocks x 16384 edges, two-phase ----
// Per-block range reservation => contiguous per-(block,bucket) write runs
// (single-XCD, temporally clustered) => L2 line coalescing for writeback.
__global__ __launch_bounds__(256) void bplace_kernel(const int* __restrict__ ei,
                                                     const int* __restrict__ bbase,
                                                     int* __restrict__ bcur,
                                                     int2* __restrict__ tmp) {
    __shared__ int h[NBK];
    __shared__ int boff[NBK];
    for (int t = threadIdx.x; t < NBK; t += 256) h[t] = 0;
    __syncthreads();
    int base = blockIdx.x * 16384;
    // phase A: local histogram
#pragma unroll 4
    for (int i = 0; i < 64; i++) {
        int e = base + i * 256 + threadIdx.x;
        if (e < EE) atomicAdd(&h[ei[EE + e] >> 8], 1);
    }
    __syncthreads();
    // reserve contiguous runs per bucket
    for (int t = threadIdx.x; t < NBK; t += 256) {
        int c = h[t];
        boff[t] = c ? (bbase[t] + atomicAdd(&bcur[t], c)) : 0;
        h[t] = 0;  // reuse as running cursor
    }
    __syncthreads();
    // phase B: place
#pragma unroll 4
    for (int i = 0; i < 64; i++) {
        int e = base + i * 256 + threadIdx.x;
        if (e < EE) {
            int s0 = ei[e];
            int d = ei[EE + e];
            int b = d >> 8;
            int p = boff[b] + atomicAdd(&h[b], 1);
            tmp[p] = make_int2(s0, d);
        }
    }
}

// ---- per-bucket local counting sort: one block per bucket ----
// Produces srcs (CSR payload), rowStart, dinv. All writes within a 16KB window.
__global__ __launch_bounds__(256) void bsort_kernel(const int2* __restrict__ tmp,
                                                    const int* __restrict__ bbase,
                                                    int* __restrict__ rowStart,
                                                    float* __restrict__ dinv,
                                                    int* __restrict__ srcs) {
    int b = blockIdx.x;
    int n0 = b << 8;
    int e0 = bbase[b], e1 = bbase[b + 1];
    int t = threadIdx.x;
    __shared__ int cnt[256];
    __shared__ int st[256];
    cnt[t] = 0;
    __syncthreads();
    for (int e = e0 + t; e < e1; e += 256) atomicAdd(&cnt[tmp[e].y - n0], 1);
    __syncthreads();
    int v = cnt[t];
    st[t] = v;
    __syncthreads();
    for (int off = 1; off < 256; off <<= 1) {
        int w = (t >= off) ? st[t - off] : 0;
        __syncthreads();
        st[t] += w;
        __syncthreads();
    }
    int excl = st[t] - v;  // in-bucket exclusive prefix
    int n = n0 + t;
    if (n < NN) {
        rowStart[n] = e0 + excl;
        dinv[n] = rsqrtf((float)v + 1.0f);
    }
    __syncthreads();
    cnt[t] = e0 + excl;  // reuse as absolute cursor
    __syncthreads();
    for (int e = e0 + t; e < e1; e += 256) {
        int2 p = tmp[e];
        int pos = atomicAdd(&cnt[p.y - n0], 1);
        srcs[pos] = p.x;
    }
}

// u[n][:] = (half) dinv[n] * (hin[n][:] @ W)   -- one thread per row
__global__ __launch_bounds__(256) void gemm_kernel(const float* __restrict__ hin,
                                                   const float* __restrict__ Wg,
                                                   const float* __restrict__ dinv,
                                                   __half* __restrict__ u) {
    int n = blockIdx.x * 256 + threadIdx.x;
    if (n >= NN) return;
    const float* hr = hin + (size_t)n * 64;
    float acc[64];
#pragma unroll
    for (int j = 0; j < 64; j++) acc[j] = 0.0f;
#pragma unroll 2
    for (int k = 0; k < 64; k++) {
        float hk = hr[k];
        const float4* Wr = (const float4*)(Wg + (k << 6));
#pragma unroll
        for (int j = 0; j < 16; j++) {
            float4 w = Wr[j];
            acc[j * 4 + 0] = fmaf(hk, w.x, acc[j * 4 + 0]);
            acc[j * 4 + 1] = fmaf(hk, w.y, acc[j * 4 + 1]);
            acc[j * 4 + 2] = fmaf(hk, w.z, acc[j * 4 + 2]);
            acc[j * 4 + 3] = fmaf(hk, w.w, acc[j * 4 + 3]);
        }
    }
    float dv = dinv[n];
    __half2* uo = (__half2*)(u + ((size_t)n << 6));
#pragma unroll
    for (int j = 0; j < 32; j++)
        uo[j] = __floats2half2_rn(acc[2 * j] * dv, acc[2 * j + 1] * dv);
}

// h_out[n] = relu(dinv[n]*(u[n] + sum_{src in CSR[n]} u[src]) + b)
// one wave per node, lane = feature; u is fp16 (128B/edge gather)
__global__ __launch_bounds__(256) void agg_kernel(const __half* __restrict__ u,
                                                  const int* __restrict__ srcs,
                                                  const int* __restrict__ rowStart,
                                                  const float* __restrict__ dinv,
                                                  const float* __restrict__ b,
                                                  float* __restrict__ hout) {
    int wid = (blockIdx.x * 256 + threadIdx.x) >> 6;
    int lane = threadIdx.x & 63;
    if (wid >= NN) return;
    int n = wid;
    float acc = __half2float(u[((size_t)n << 6) + lane]);
    int e = rowStart[n];
    int e1 = rowStart[n + 1];
    for (; e + 3 < e1; e += 4) {
        int s0 = srcs[e + 0];
        int s1 = srcs[e + 1];
        int s2 = srcs[e + 2];
        int s3 = srcs[e + 3];
        float v0 = __half2float(u[((size_t)s0 << 6) + lane]);
        float v1 = __half2float(u[((size_t)s1 << 6) + lane]);
        float v2 = __half2float(u[((size_t)s2 << 6) + lane]);
        float v3 = __half2float(u[((size_t)s3 << 6) + lane]);
        acc += v0;
        acc += v1;
        acc += v2;
        acc += v3;
    }
    for (; e < e1; e++) {
        int s0 = srcs[e];
        acc += __half2float(u[((size_t)s0 << 6) + lane]);
    }
    float v = fmaf(dinv[n], acc, b[lane]);
    hout[((size_t)n << 6) + lane] = fmaxf(v, 0.0f);
}

// mean-pool partials: one wave per 256 contiguous nodes (batch is sorted)
__global__ __launch_bounds__(256) void pool_kernel(const float* __restrict__ hbuf,
                                                   const int* __restrict__ batch,
                                                   float* __restrict__ gsum,
                                                   float* __restrict__ gcnt) {
    int wave = (blockIdx.x * 256 + threadIdx.x) >> 6;
    int lane = threadIdx.x & 63;
    int n0 = wave * 256;
    if (n0 >= NN) return;
    int n1 = n0 + 256;
    if (n1 > NN) n1 = NN;
    int curg = batch[n0];
    float racc = 0.0f;
    float rcnt = 0.0f;
    for (int n = n0; n < n1; n++) {
        int g = batch[n];
        if (g != curg) {
            atomicAdd(&gsum[curg * 64 + lane], racc);
            if (lane == 0) atomicAdd(&gcnt[curg], rcnt);
            racc = 0.0f;
            rcnt = 0.0f;
            curg = g;
        }
        racc += hbuf[((size_t)n << 6) + lane];
        rcnt += 1.0f;
    }
    atomicAdd(&gsum[curg * 64 + lane], racc);
    if (lane == 0) atomicAdd(&gcnt[curg], rcnt);
}

__global__ __launch_bounds__(128) void final_kernel(const float* __restrict__ gsum,
                                                    const float* __restrict__ gcnt,
                                                    const float* __restrict__ Wlin,
                                                    const float* __restrict__ blin,
                                                    float* __restrict__ out) {
    int t = threadIdx.x;  // 128 = G*C
    int g = t >> 1;
    int c = t & 1;
    float cnt = fmaxf(gcnt[g], 1.0f);
    float s = 0.0f;
#pragma unroll
    for (int k = 0; k < 64; k++) s = fmaf(gsum[g * 64 + k], Wlin[k * 2 + c], s);
    out[t] = s / cnt + blin[c];
}

extern "C" void kernel_launch(void* const* d_in, const int* in_sizes, int n_in,
                              void* d_out, int out_size, void* d_ws, size_t ws_size,
                              hipStream_t stream) {
    const float* x     = (const float*)d_in[0];
    const int*   ei    = (const int*)d_in[1];
    const int*   batch = (const int*)d_in[2];
    const float* W0    = (const float*)d_in[3];
    const float* b0    = (const float*)d_in[4];
    const float* W1    = (const float*)d_in[5];
    const float* b1    = (const float*)d_in[6];
    const float* W2    = (const float*)d_in[7];
    const float* b2    = (const float*)d_in[8];
    const float* Wlin  = (const float*)d_in[9];
    const float* blin  = (const float*)d_in[10];
    float* out = (float*)d_out;

    char* ws = (char*)d_ws;
    int*    rowStart = (int*)(ws + 0);
    float*  dinv     = (float*)(ws + 400128);
    int*    srcs     = (int*)(ws + 800128);
    int2*   tmp      = (int2*)(ws + 7200128);
    __half* u        = (__half*)(ws + 20000128);
    float*  hb       = (float*)(ws + 32800128);
    float*  gsum     = (float*)(ws + 58400128);
    float*  gcnt     = (float*)(ws + 58416512);
    int*    bcnt     = (int*)(ws + 58416768);
    int*    bbase    = (int*)(ws + 58418816);
    int*    bcur     = (int*)(ws + 58420864);

    // zero gsum+gcnt+bcnt+bbase+bcur in one contiguous memset
    hipMemsetAsync(ws + 58400128, 0, 22784, stream);

    // CSR build: bucket count -> scan -> partition -> per-bucket sort
    bcount_kernel<<<cdiv_h(EE, 4096), 256, 0, stream>>>(ei, bcnt);
    bscan_kernel<<<1, 512, 0, stream>>>(bcnt, bbase, rowStart);
    bplace_kernel<<<cdiv_h(EE, 16384), 256, 0, stream>>>(ei, bbase, bcur, tmp);
    bsort_kernel<<<NBK, 256, 0, stream>>>(tmp, bbase, rowStart, dinv, srcs);

    int gemm_blocks = cdiv_h(NN, 256);
    int agg_blocks = cdiv_h(NN, 4);  // 4 waves (nodes) per block

    gemm_kernel<<<gemm_blocks, 256, 0, stream>>>(x, W0, dinv, u);
    agg_kernel<<<agg_blocks, 256, 0, stream>>>(u, srcs, rowStart, dinv, b0, hb);
    gemm_kernel<<<gemm_blocks, 256, 0, stream>>>(hb, W1, dinv, u);
    agg_kernel<<<agg_blocks, 256, 0, stream>>>(u, srcs, rowStart, dinv, b1, hb);
    gemm_kernel<<<gemm_blocks, 256, 0, stream>>>(hb, W2, dinv, u);
    agg_kernel<<<agg_blocks, 256, 0, stream>>>(u, srcs, rowStart, dinv, b2, hb);

    pool_kernel<<<cdiv_h(cdiv_h(NN, 256), 4), 256, 0, stream>>>(hb, batch, gsum, gcnt);
    final_kernel<<<1, 128, 0, stream>>>(gsum, gcnt, Wlin, blin, out);
}

// Round 4
// 466.296 us; speedup vs baseline: 1.8445x; 1.1321x over previous
//
#include <hip/hip_runtime.h>
#include <hip/hip_fp16.h>

#define NN 100000
#define EE 1600000
#define HH 64
#define GG 64
#define NBK 391   // buckets of 256 nodes: dst>>8, ceil(100000/256)

// ---------------- workspace layout (bytes) ----------------
// rowStart : int[NN+1]    @ 0
// dinv     : float[NN]    @ 400128
// srcs     : int[EE]      @ 800128
// tmp      : int2[EE]     @ 7200128
// u (half) : half[NN*64]  @ 20000128
// hb       : float[NN*64] @ 32800128
// gsum     : float[4096]  @ 58400128
// gcnt     : float[64]    @ 58416512
// bcnt     : int[NBK]     @ 58416768
// bbase    : int[NBK+1]   @ 58418816
// bcur     : int[NBK]     @ 58420864

static inline int cdiv_h(int a, int b) { return (a + b - 1) / b; }

// ---- bucket histogram: 391 blocks x 4096 edges, LDS pre-aggregation ----
__global__ __launch_bounds__(256) void bcount_kernel(const int* __restrict__ ei,
                                                     int* __restrict__ bcnt) {
    __shared__ int h[NBK];
    for (int t = threadIdx.x; t < NBK; t += 256) h[t] = 0;
    __syncthreads();
    int base = blockIdx.x * 4096;
#pragma unroll
    for (int i = 0; i < 16; i++) {
        int e = base + i * 256 + threadIdx.x;
        if (e < EE) atomicAdd(&h[ei[EE + e] >> 8], 1);
    }
    __syncthreads();
    for (int t = threadIdx.x; t < NBK; t += 256)
        if (h[t]) atomicAdd(&bcnt[t], h[t]);
}

// ---- scan 391 bucket counts (1 block) ----
__global__ __launch_bounds__(512) void bscan_kernel(const int* __restrict__ bcnt,
                                                    int* __restrict__ bbase,
                                                    int* __restrict__ rowStart) {
    __shared__ int s[512];
    int t = threadIdx.x;
    int v = (t < NBK) ? bcnt[t] : 0;
    s[t] = v;
    __syncthreads();
    for (int off = 1; off < 512; off <<= 1) {
        int w = (t >= off) ? s[t - off] : 0;
        __syncthreads();
        s[t] += w;
        __syncthreads();
    }
    if (t < NBK) bbase[t] = s[t] - v;  // exclusive
    if (t == 0) { bbase[NBK] = EE; rowStart[NN] = EE; }
}

// ---- partition edges into buckets: 98 blocks x 16384 edges, two-phase ----
__global__ __launch_bounds__(256) void bplace_kernel(const int* __restrict__ ei,
                                                     const int* __restrict__ bbase,
                                                     int* __restrict__ bcur,
                                                     int2* __restrict__ tmp) {
    __shared__ int h[NBK];
    __shared__ int boff[NBK];
    for (int t = threadIdx.x; t < NBK; t += 256) h[t] = 0;
    __syncthreads();
    int base = blockIdx.x * 16384;
#pragma unroll 4
    for (int i = 0; i < 64; i++) {
        int e = base + i * 256 + threadIdx.x;
        if (e < EE) atomicAdd(&h[ei[EE + e] >> 8], 1);
    }
    __syncthreads();
    for (int t = threadIdx.x; t < NBK; t += 256) {
        int c = h[t];
        boff[t] = c ? (bbase[t] + atomicAdd(&bcur[t], c)) : 0;
        h[t] = 0;  // reuse as running cursor
    }
    __syncthreads();
#pragma unroll 4
    for (int i = 0; i < 64; i++) {
        int e = base + i * 256 + threadIdx.x;
        if (e < EE) {
            int s0 = ei[e];
            int d = ei[EE + e];
            int b = d >> 8;
            int p = boff[b] + atomicAdd(&h[b], 1);
            tmp[p] = make_int2(s0, d);
        }
    }
}

// ---- per-bucket local counting sort: one block per bucket ----
__global__ __launch_bounds__(256) void bsort_kernel(const int2* __restrict__ tmp,
                                                    const int* __restrict__ bbase,
                                                    int* __restrict__ rowStart,
                                                    float* __restrict__ dinv,
                                                    int* __restrict__ srcs) {
    int b = blockIdx.x;
    int n0 = b << 8;
    int e0 = bbase[b], e1 = bbase[b + 1];
    int t = threadIdx.x;
    __shared__ int cnt[256];
    __shared__ int st[256];
    cnt[t] = 0;
    __syncthreads();
    for (int e = e0 + t; e < e1; e += 256) atomicAdd(&cnt[tmp[e].y - n0], 1);
    __syncthreads();
    int v = cnt[t];
    st[t] = v;
    __syncthreads();
    for (int off = 1; off < 256; off <<= 1) {
        int w = (t >= off) ? st[t - off] : 0;
        __syncthreads();
        st[t] += w;
        __syncthreads();
    }
    int excl = st[t] - v;
    int n = n0 + t;
    if (n < NN) {
        rowStart[n] = e0 + excl;
        dinv[n] = rsqrtf((float)v + 1.0f);
    }
    __syncthreads();
    cnt[t] = e0 + excl;  // absolute cursor
    __syncthreads();
    for (int e = e0 + t; e < e1; e += 256) {
        int2 p = tmp[e];
        int pos = atomicAdd(&cnt[p.y - n0], 1);
        srcs[pos] = p.x;
    }
}

// ---- gcnt: parallel LDS histogram over sorted batch ids ----
__global__ __launch_bounds__(256) void gcnt_kernel(const int* __restrict__ batch,
                                                   float* __restrict__ gcnt) {
    __shared__ int h[GG];
    if (threadIdx.x < GG) h[threadIdx.x] = 0;
    __syncthreads();
    int n = blockIdx.x * 256 + threadIdx.x;
    if (n < NN) atomicAdd(&h[batch[n]], 1);
    __syncthreads();
    if (threadIdx.x < GG && h[threadIdx.x])
        atomicAdd(&gcnt[threadIdx.x], (float)h[threadIdx.x]);
}

// u[n][:] = (half) dinv[n] * (hin[n][:] @ W)   -- one thread per row
__global__ __launch_bounds__(256) void gemm_kernel(const float* __restrict__ hin,
                                                   const float* __restrict__ Wg,
                                                   const float* __restrict__ dinv,
                                                   __half* __restrict__ u) {
    int n = blockIdx.x * 256 + threadIdx.x;
    if (n >= NN) return;
    const float* hr = hin + (size_t)n * 64;
    float acc[64];
#pragma unroll
    for (int j = 0; j < 64; j++) acc[j] = 0.0f;
#pragma unroll 2
    for (int k = 0; k < 64; k++) {
        float hk = hr[k];
        const float4* Wr = (const float4*)(Wg + (k << 6));
#pragma unroll
        for (int j = 0; j < 16; j++) {
            float4 w = Wr[j];
            acc[j * 4 + 0] = fmaf(hk, w.x, acc[j * 4 + 0]);
            acc[j * 4 + 1] = fmaf(hk, w.y, acc[j * 4 + 1]);
            acc[j * 4 + 2] = fmaf(hk, w.z, acc[j * 4 + 2]);
            acc[j * 4 + 3] = fmaf(hk, w.w, acc[j * 4 + 3]);
        }
    }
    float dv = dinv[n];
    __half2* uo = (__half2*)(u + ((size_t)n << 6));
#pragma unroll
    for (int j = 0; j < 32; j++)
        uo[j] = __floats2half2_rn(acc[2 * j] * dv, acc[2 * j + 1] * dv);
}

// gather core: acc = u[n] + sum_{src} u[src]  (fp32 accumulate of fp16 u)
__device__ __forceinline__ float agg_gather(const __half* __restrict__ u,
                                            const int* __restrict__ srcs,
                                            int n, int lane, int e, int e1) {
    float acc = __half2float(u[((size_t)n << 6) + lane]);
    for (; e + 3 < e1; e += 4) {
        int s0 = srcs[e + 0];
        int s1 = srcs[e + 1];
        int s2 = srcs[e + 2];
        int s3 = srcs[e + 3];
        float v0 = __half2float(u[((size_t)s0 << 6) + lane]);
        float v1 = __half2float(u[((size_t)s1 << 6) + lane]);
        float v2 = __half2float(u[((size_t)s2 << 6) + lane]);
        float v3 = __half2float(u[((size_t)s3 << 6) + lane]);
        acc += v0;
        acc += v1;
        acc += v2;
        acc += v3;
    }
    for (; e < e1; e++) acc += __half2float(u[((size_t)srcs[e] << 6) + lane]);
    return acc;
}

// layers 0,1: h_out[n] = relu(dinv[n]*gather + b)
__global__ __launch_bounds__(256) void agg_kernel(const __half* __restrict__ u,
                                                  const int* __restrict__ srcs,
                                                  const int* __restrict__ rowStart,
                                                  const float* __restrict__ dinv,
                                                  const float* __restrict__ b,
                                                  float* __restrict__ hout) {
    int wid = (blockIdx.x * 256 + threadIdx.x) >> 6;
    int lane = threadIdx.x & 63;
    if (wid >= NN) return;
    int n = wid;
    float acc = agg_gather(u, srcs, n, lane, rowStart[n], rowStart[n + 1]);
    float v = fmaf(dinv[n], acc, b[lane]);
    hout[((size_t)n << 6) + lane] = fmaxf(v, 0.0f);
}

// layer 2 fused with mean-pool partial sums: no hb write, LDS-reduce 4 nodes
// per block (consecutive node ids => usually same graph), 1 atomic/graph/block.
__global__ __launch_bounds__(256) void agg_pool_kernel(const __half* __restrict__ u,
                                                       const int* __restrict__ srcs,
                                                       const int* __restrict__ rowStart,
                                                       const float* __restrict__ dinv,
                                                       const float* __restrict__ b,
                                                       const int* __restrict__ batch,
                                                       float* __restrict__ gsum) {
    int wid = (blockIdx.x * 256 + threadIdx.x) >> 6;
    int w = threadIdx.x >> 6;
    int lane = threadIdx.x & 63;
    __shared__ float vals[4][64];
    __shared__ int gid[4];
    float v = 0.0f;
    int g = -1;
    if (wid < NN) {
        int n = wid;
        float acc = agg_gather(u, srcs, n, lane, rowStart[n], rowStart[n + 1]);
        v = fmaxf(fmaf(dinv[n], acc, b[lane]), 0.0f);
        g = batch[n];
    }
    vals[w][lane] = v;
    if (lane == 0) gid[w] = g;
    __syncthreads();
    if (w == 0) {
#pragma unroll
        for (int j = 0; j < 4; j++) {
            int gj = gid[j];
            if (gj < 0) continue;
            bool first = true;
#pragma unroll
            for (int k = 0; k < 4; k++)
                if (k < j && gid[k] == gj) first = false;
            if (first) {
                float s = vals[j][lane];
#pragma unroll
                for (int k = 0; k < 4; k++)
                    if (k > j && gid[k] == gj) s += vals[k][lane];
                atomicAdd(&gsum[gj * 64 + lane], s);
            }
        }
    }
}

__global__ __launch_bounds__(128) void final_kernel(const float* __restrict__ gsum,
                                                    const float* __restrict__ gcnt,
                                                    const float* __restrict__ Wlin,
                                                    const float* __restrict__ blin,
                                                    float* __restrict__ out) {
    int t = threadIdx.x;  // 128 = G*C
    int g = t >> 1;
    int c = t & 1;
    float cnt = fmaxf(gcnt[g], 1.0f);
    float s = 0.0f;
#pragma unroll
    for (int k = 0; k < 64; k++) s = fmaf(gsum[g * 64 + k], Wlin[k * 2 + c], s);
    out[t] = s / cnt + blin[c];
}

extern "C" void kernel_launch(void* const* d_in, const int* in_sizes, int n_in,
                              void* d_out, int out_size, void* d_ws, size_t ws_size,
                              hipStream_t stream) {
    const float* x     = (const float*)d_in[0];
    const int*   ei    = (const int*)d_in[1];
    const int*   batch = (const int*)d_in[2];
    const float* W0    = (const float*)d_in[3];
    const float* b0    = (const float*)d_in[4];
    const float* W1    = (const float*)d_in[5];
    const float* b1    = (const float*)d_in[6];
    const float* W2    = (const float*)d_in[7];
    const float* b2    = (const float*)d_in[8];
    const float* Wlin  = (const float*)d_in[9];
    const float* blin  = (const float*)d_in[10];
    float* out = (float*)d_out;

    char* ws = (char*)d_ws;
    int*    rowStart = (int*)(ws + 0);
    float*  dinv     = (float*)(ws + 400128);
    int*    srcs     = (int*)(ws + 800128);
    int2*   tmp      = (int2*)(ws + 7200128);
    __half* u        = (__half*)(ws + 20000128);
    float*  hb       = (float*)(ws + 32800128);
    float*  gsum     = (float*)(ws + 58400128);
    float*  gcnt     = (float*)(ws + 58416512);
    int*    bcnt     = (int*)(ws + 58416768);
    int*    bbase    = (int*)(ws + 58418816);
    int*    bcur     = (int*)(ws + 58420864);

    // zero gsum+gcnt+bcnt+bbase+bcur in one contiguous memset
    hipMemsetAsync(ws + 58400128, 0, 22784, stream);

    // CSR build: bucket count -> scan -> partition -> per-bucket sort
    bcount_kernel<<<cdiv_h(EE, 4096), 256, 0, stream>>>(ei, bcnt);
    bscan_kernel<<<1, 512, 0, stream>>>(bcnt, bbase, rowStart);
    bplace_kernel<<<cdiv_h(EE, 16384), 256, 0, stream>>>(ei, bbase, bcur, tmp);
    bsort_kernel<<<NBK, 256, 0, stream>>>(tmp, bbase, rowStart, dinv, srcs);
    gcnt_kernel<<<NBK, 256, 0, stream>>>(batch, gcnt);

    int gemm_blocks = cdiv_h(NN, 256);
    int agg_blocks = cdiv_h(NN, 4);  // 4 waves (nodes) per block

    gemm_kernel<<<gemm_blocks, 256, 0, stream>>>(x, W0, dinv, u);
    agg_kernel<<<agg_blocks, 256, 0, stream>>>(u, srcs, rowStart, dinv, b0, hb);
    gemm_kernel<<<gemm_blocks, 256, 0, stream>>>(hb, W1, dinv, u);
    agg_kernel<<<agg_blocks, 256, 0, stream>>>(u, srcs, rowStart, dinv, b1, hb);
    gemm_kernel<<<gemm_blocks, 256, 0, stream>>>(hb, W2, dinv, u);
    agg_pool_kernel<<<agg_blocks, 256, 0, stream>>>(u, srcs, rowStart, dinv, b2, batch, gsum);

    final_kernel<<<1, 128, 0, stream>>>(gsum, gcnt, Wlin, blin, out);
}

// Round 5
// 418.693 us; speedup vs baseline: 2.0542x; 1.1137x over previous
//
#include <hip/hip_runtime.h>
#include <hip/hip_fp16.h>

#define NN 100000
#define EE 1600000
#define HH 64
#define GG 64
#define NBK 391   // buckets of 256 nodes: dst>>8, ceil(100000/256)

// ---------------- workspace layout (bytes) ----------------
// rowStart : int[NN+1]    @ 0
// dinv     : float[NN]    @ 400128
// srcs     : int[EE]      @ 800128
// tmp      : int2[EE]     @ 7200128
// u (half) : half[NN*64]  @ 20000128
// hb       : float[NN*64] @ 32800128
// gsum     : float[4096]  @ 58400128
// gcnt     : float[64]    @ 58416512
// bcnt     : int[NBK]     @ 58416768
// bbase    : int[NBK+1]   @ 58418816
// bcur     : int[NBK]     @ 58420864

static inline int cdiv_h(int a, int b) { return (a + b - 1) / b; }

struct H4 { __half2 a, b; };  // 8 bytes = 4 fp16 features

// ---- bucket histogram: 391 blocks x 4096 edges, LDS pre-aggregation ----
__global__ __launch_bounds__(256) void bcount_kernel(const int* __restrict__ ei,
                                                     int* __restrict__ bcnt) {
    __shared__ int h[NBK];
    for (int t = threadIdx.x; t < NBK; t += 256) h[t] = 0;
    __syncthreads();
    int base = blockIdx.x * 4096;
#pragma unroll
    for (int i = 0; i < 16; i++) {
        int e = base + i * 256 + threadIdx.x;
        if (e < EE) atomicAdd(&h[ei[EE + e] >> 8], 1);
    }
    __syncthreads();
    for (int t = threadIdx.x; t < NBK; t += 256)
        if (h[t]) atomicAdd(&bcnt[t], h[t]);
}

// ---- scan 391 bucket counts (1 block) ----
__global__ __launch_bounds__(512) void bscan_kernel(const int* __restrict__ bcnt,
                                                    int* __restrict__ bbase,
                                                    int* __restrict__ rowStart) {
    __shared__ int s[512];
    int t = threadIdx.x;
    int v = (t < NBK) ? bcnt[t] : 0;
    s[t] = v;
    __syncthreads();
    for (int off = 1; off < 512; off <<= 1) {
        int w = (t >= off) ? s[t - off] : 0;
        __syncthreads();
        s[t] += w;
        __syncthreads();
    }
    if (t < NBK) bbase[t] = s[t] - v;  // exclusive
    if (t == 0) { bbase[NBK] = EE; rowStart[NN] = EE; }
}

// ---- partition edges into buckets: 98 blocks x 16384 edges, two-phase ----
__global__ __launch_bounds__(256) void bplace_kernel(const int* __restrict__ ei,
                                                     const int* __restrict__ bbase,
                                                     int* __restrict__ bcur,
                                                     int2* __restrict__ tmp) {
    __shared__ int h[NBK];
    __shared__ int boff[NBK];
    for (int t = threadIdx.x; t < NBK; t += 256) h[t] = 0;
    __syncthreads();
    int base = blockIdx.x * 16384;
#pragma unroll 4
    for (int i = 0; i < 64; i++) {
        int e = base + i * 256 + threadIdx.x;
        if (e < EE) atomicAdd(&h[ei[EE + e] >> 8], 1);
    }
    __syncthreads();
    for (int t = threadIdx.x; t < NBK; t += 256) {
        int c = h[t];
        boff[t] = c ? (bbase[t] + atomicAdd(&bcur[t], c)) : 0;
        h[t] = 0;  // reuse as running cursor
    }
    __syncthreads();
#pragma unroll 4
    for (int i = 0; i < 64; i++) {
        int e = base + i * 256 + threadIdx.x;
        if (e < EE) {
            int s0 = ei[e];
            int d = ei[EE + e];
            int b = d >> 8;
            int p = boff[b] + atomicAdd(&h[b], 1);
            tmp[p] = make_int2(s0, d);
        }
    }
}

// ---- per-bucket local counting sort: one block per bucket ----
__global__ __launch_bounds__(256) void bsort_kernel(const int2* __restrict__ tmp,
                                                    const int* __restrict__ bbase,
                                                    int* __restrict__ rowStart,
                                                    float* __restrict__ dinv,
                                                    int* __restrict__ srcs) {
    int b = blockIdx.x;
    int n0 = b << 8;
    int e0 = bbase[b], e1 = bbase[b + 1];
    int t = threadIdx.x;
    __shared__ int cnt[256];
    __shared__ int st[256];
    cnt[t] = 0;
    __syncthreads();
    for (int e = e0 + t; e < e1; e += 256) atomicAdd(&cnt[tmp[e].y - n0], 1);
    __syncthreads();
    int v = cnt[t];
    st[t] = v;
    __syncthreads();
    for (int off = 1; off < 256; off <<= 1) {
        int w = (t >= off) ? st[t - off] : 0;
        __syncthreads();
        st[t] += w;
        __syncthreads();
    }
    int excl = st[t] - v;
    int n = n0 + t;
    if (n < NN) {
        rowStart[n] = e0 + excl;
        dinv[n] = rsqrtf((float)v + 1.0f);
    }
    __syncthreads();
    cnt[t] = e0 + excl;  // absolute cursor
    __syncthreads();
    for (int e = e0 + t; e < e1; e += 256) {
        int2 p = tmp[e];
        int pos = atomicAdd(&cnt[p.y - n0], 1);
        srcs[pos] = p.x;
    }
}

// ---- gcnt: parallel LDS histogram over sorted batch ids ----
__global__ __launch_bounds__(256) void gcnt_kernel(const int* __restrict__ batch,
                                                   float* __restrict__ gcnt) {
    __shared__ int h[GG];
    if (threadIdx.x < GG) h[threadIdx.x] = 0;
    __syncthreads();
    int n = blockIdx.x * 256 + threadIdx.x;
    if (n < NN) atomicAdd(&h[batch[n]], 1);
    __syncthreads();
    if (threadIdx.x < GG && h[threadIdx.x])
        atomicAdd(&gcnt[threadIdx.x], (float)h[threadIdx.x]);
}

// u[n][:] = (half) dinv[n] * (hin[n][:] @ W)   -- one thread per row
__global__ __launch_bounds__(256) void gemm_kernel(const float* __restrict__ hin,
                                                   const float* __restrict__ Wg,
                                                   const float* __restrict__ dinv,
                                                   __half* __restrict__ u) {
    int n = blockIdx.x * 256 + threadIdx.x;
    if (n >= NN) return;
    const float* hr = hin + (size_t)n * 64;
    float acc[64];
#pragma unroll
    for (int j = 0; j < 64; j++) acc[j] = 0.0f;
#pragma unroll 2
    for (int k = 0; k < 64; k++) {
        float hk = hr[k];
        const float4* Wr = (const float4*)(Wg + (k << 6));
#pragma unroll
        for (int j = 0; j < 16; j++) {
            float4 w = Wr[j];
            acc[j * 4 + 0] = fmaf(hk, w.x, acc[j * 4 + 0]);
            acc[j * 4 + 1] = fmaf(hk, w.y, acc[j * 4 + 1]);
            acc[j * 4 + 2] = fmaf(hk, w.z, acc[j * 4 + 2]);
            acc[j * 4 + 3] = fmaf(hk, w.w, acc[j * 4 + 3]);
        }
    }
    float dv = dinv[n];
    __half2* uo = (__half2*)(u + ((size_t)n << 6));
#pragma unroll
    for (int j = 0; j < 32; j++)
        uo[j] = __floats2half2_rn(acc[2 * j] * dv, acc[2 * j + 1] * dv);
}

// ---- gather core: 16 lanes per edge, 8B (4-feature) loads, 4 edges/inst ----
// lane = 16*sub + fl; lane fl accumulates features 4*fl..4*fl+3 of edges
// {e0+sub, e0+sub+4, ...}. Caller must shuffle-reduce over sub (xor 16, 32).
__device__ __forceinline__ void agg_gather4(const __half* __restrict__ u,
                                            const int* __restrict__ srcs,
                                            int n, int sub, int fl, int e0, int e1,
                                            float& a0, float& a1, float& a2, float& a3) {
    a0 = a1 = a2 = a3 = 0.0f;
    if (sub == 0) {
        H4 r = *(const H4*)(u + ((size_t)n << 6) + (fl << 2));
        float2 f0 = __half22float2(r.a), f1 = __half22float2(r.b);
        a0 = f0.x; a1 = f0.y; a2 = f1.x; a3 = f1.y;
    }
    int e = e0 + sub;
    for (; e + 4 < e1; e += 8) {
        int sA = srcs[e];
        int sB = srcs[e + 4];
        H4 ra = *(const H4*)(u + ((size_t)sA << 6) + (fl << 2));
        H4 rb = *(const H4*)(u + ((size_t)sB << 6) + (fl << 2));
        float2 fa0 = __half22float2(ra.a), fa1 = __half22float2(ra.b);
        float2 fb0 = __half22float2(rb.a), fb1 = __half22float2(rb.b);
        a0 += fa0.x; a1 += fa0.y; a2 += fa1.x; a3 += fa1.y;
        a0 += fb0.x; a1 += fb0.y; a2 += fb1.x; a3 += fb1.y;
    }
    if (e < e1) {
        int sA = srcs[e];
        H4 ra = *(const H4*)(u + ((size_t)sA << 6) + (fl << 2));
        float2 fa0 = __half22float2(ra.a), fa1 = __half22float2(ra.b);
        a0 += fa0.x; a1 += fa0.y; a2 += fa1.x; a3 += fa1.y;
    }
}

__device__ __forceinline__ void sub_reduce(float& a0, float& a1, float& a2, float& a3) {
    a0 += __shfl_xor(a0, 16); a1 += __shfl_xor(a1, 16);
    a2 += __shfl_xor(a2, 16); a3 += __shfl_xor(a3, 16);
    a0 += __shfl_xor(a0, 32); a1 += __shfl_xor(a1, 32);
    a2 += __shfl_xor(a2, 32); a3 += __shfl_xor(a3, 32);
}

// layers 0,1: h_out[n] = relu(dinv[n]*gather + b)
__global__ __launch_bounds__(256) void agg_kernel(const __half* __restrict__ u,
                                                  const int* __restrict__ srcs,
                                                  const int* __restrict__ rowStart,
                                                  const float* __restrict__ dinv,
                                                  const float* __restrict__ b,
                                                  float* __restrict__ hout) {
    int wid = (blockIdx.x * 256 + threadIdx.x) >> 6;
    int lane = threadIdx.x & 63;
    int sub = lane >> 4, fl = lane & 15;
    if (wid >= NN) return;
    int n = wid;
    float a0, a1, a2, a3;
    agg_gather4(u, srcs, n, sub, fl, rowStart[n], rowStart[n + 1], a0, a1, a2, a3);
    sub_reduce(a0, a1, a2, a3);
    if (sub == 0) {
        float dv = dinv[n];
        float4 bb = *(const float4*)(b + (fl << 2));
        float4 r;
        r.x = fmaxf(fmaf(dv, a0, bb.x), 0.0f);
        r.y = fmaxf(fmaf(dv, a1, bb.y), 0.0f);
        r.z = fmaxf(fmaf(dv, a2, bb.z), 0.0f);
        r.w = fmaxf(fmaf(dv, a3, bb.w), 0.0f);
        *(float4*)(hout + ((size_t)n << 6) + (fl << 2)) = r;
    }
}

// layer 2 fused with mean-pool partial sums
__global__ __launch_bounds__(256) void agg_pool_kernel(const __half* __restrict__ u,
                                                       const int* __restrict__ srcs,
                                                       const int* __restrict__ rowStart,
                                                       const float* __restrict__ dinv,
                                                       const float* __restrict__ b,
                                                       const int* __restrict__ batch,
                                                       float* __restrict__ gsum) {
    int wid = (blockIdx.x * 256 + threadIdx.x) >> 6;
    int w = threadIdx.x >> 6;
    int lane = threadIdx.x & 63;
    int sub = lane >> 4, fl = lane & 15;
    __shared__ float vals[4][64];
    __shared__ int gid[4];
    float4 r = make_float4(0.f, 0.f, 0.f, 0.f);
    int g = -1;
    if (wid < NN) {
        int n = wid;
        float a0, a1, a2, a3;
        agg_gather4(u, srcs, n, sub, fl, rowStart[n], rowStart[n + 1], a0, a1, a2, a3);
        sub_reduce(a0, a1, a2, a3);
        float dv = dinv[n];
        float4 bb = *(const float4*)(b + (fl << 2));
        r.x = fmaxf(fmaf(dv, a0, bb.x), 0.0f);
        r.y = fmaxf(fmaf(dv, a1, bb.y), 0.0f);
        r.z = fmaxf(fmaf(dv, a2, bb.z), 0.0f);
        r.w = fmaxf(fmaf(dv, a3, bb.w), 0.0f);
        g = batch[n];
    }
    if (sub == 0) *(float4*)(&vals[w][fl << 2]) = r;
    if (lane == 0) gid[w] = g;
    __syncthreads();
    if (w == 0) {
#pragma unroll
        for (int j = 0; j < 4; j++) {
            int gj = gid[j];
            if (gj < 0) continue;
            bool first = true;
#pragma unroll
            for (int k = 0; k < 4; k++)
                if (k < j && gid[k] == gj) first = false;
            if (first) {
                float s = vals[j][lane];
#pragma unroll
                for (int k = 0; k < 4; k++)
                    if (k > j && gid[k] == gj) s += vals[k][lane];
                atomicAdd(&gsum[gj * 64 + lane], s);
            }
        }
    }
}

__global__ __launch_bounds__(128) void final_kernel(const float* __restrict__ gsum,
                                                    const float* __restrict__ gcnt,
                                                    const float* __restrict__ Wlin,
                                                    const float* __restrict__ blin,
                                                    float* __restrict__ out) {
    int t = threadIdx.x;  // 128 = G*C
    int g = t >> 1;
    int c = t & 1;
    float cnt = fmaxf(gcnt[g], 1.0f);
    float s = 0.0f;
#pragma unroll
    for (int k = 0; k < 64; k++) s = fmaf(gsum[g * 64 + k], Wlin[k * 2 + c], s);
    out[t] = s / cnt + blin[c];
}

extern "C" void kernel_launch(void* const* d_in, const int* in_sizes, int n_in,
                              void* d_out, int out_size, void* d_ws, size_t ws_size,
                              hipStream_t stream) {
    const float* x     = (const float*)d_in[0];
    const int*   ei    = (const int*)d_in[1];
    const int*   batch = (const int*)d_in[2];
    const float* W0    = (const float*)d_in[3];
    const float* b0    = (const float*)d_in[4];
    const float* W1    = (const float*)d_in[5];
    const float* b1    = (const float*)d_in[6];
    const float* W2    = (const float*)d_in[7];
    const float* b2    = (const float*)d_in[8];
    const float* Wlin  = (const float*)d_in[9];
    const float* blin  = (const float*)d_in[10];
    float* out = (float*)d_out;

    char* ws = (char*)d_ws;
    int*    rowStart = (int*)(ws + 0);
    float*  dinv     = (float*)(ws + 400128);
    int*    srcs     = (int*)(ws + 800128);
    int2*   tmp      = (int2*)(ws + 7200128);
    __half* u        = (__half*)(ws + 20000128);
    float*  hb       = (float*)(ws + 32800128);
    float*  gsum     = (float*)(ws + 58400128);
    float*  gcnt     = (float*)(ws + 58416512);
    int*    bcnt     = (int*)(ws + 58416768);
    int*    bbase    = (int*)(ws + 58418816);
    int*    bcur     = (int*)(ws + 58420864);

    // zero gsum+gcnt+bcnt+bbase+bcur in one contiguous memset
    hipMemsetAsync(ws + 58400128, 0, 22784, stream);

    // CSR build: bucket count -> scan -> partition -> per-bucket sort
    bcount_kernel<<<cdiv_h(EE, 4096), 256, 0, stream>>>(ei, bcnt);
    bscan_kernel<<<1, 512, 0, stream>>>(bcnt, bbase, rowStart);
    bplace_kernel<<<cdiv_h(EE, 16384), 256, 0, stream>>>(ei, bbase, bcur, tmp);
    bsort_kernel<<<NBK, 256, 0, stream>>>(tmp, bbase, rowStart, dinv, srcs);
    gcnt_kernel<<<NBK, 256, 0, stream>>>(batch, gcnt);

    int gemm_blocks = cdiv_h(NN, 256);
    int agg_blocks = cdiv_h(NN, 4);  // 4 waves (nodes) per block

    gemm_kernel<<<gemm_blocks, 256, 0, stream>>>(x, W0, dinv, u);
    agg_kernel<<<agg_blocks, 256, 0, stream>>>(u, srcs, rowStart, dinv, b0, hb);
    gemm_kernel<<<gemm_blocks, 256, 0, stream>>>(hb, W1, dinv, u);
    agg_kernel<<<agg_blocks, 256, 0, stream>>>(u, srcs, rowStart, dinv, b1, hb);
    gemm_kernel<<<gemm_blocks, 256, 0, stream>>>(hb, W2, dinv, u);
    agg_pool_kernel<<<agg_blocks, 256, 0, stream>>>(u, srcs, rowStart, dinv, b2, batch, gsum);

    final_kernel<<<1, 128, 0, stream>>>(gsum, gcnt, Wlin, blin, out);
}